// Round 1
// baseline (426.459 us; speedup 1.0000x reference)
//
#include <hip/hip_runtime.h>
#include <stdint.h>

typedef unsigned long long u64;
typedef unsigned int u32;

#define N_IMG 32
#define C_IN  256
#define C_OUT 256
#define H     56
#define W     56
#define HW    (H*W)          // 3136
#define NHW   (N_IMG*HW)     // 100352
#define CHW   (C_IN*HW)      // 802816

// Workspace layout:
//   px: [n][h][w][4] u64 packed sign bits of x      (401408 * 8 = 3,211,264 B)
//   pw: [co][tap(9)][4] u64 packed sign bits of w   (9216   * 8 =    73,728 B)
//   y : [n][co][h][w] int16 exact conv result       (25,690,112 * 2 = 51,380,224 B)
#define PX_BYTES 3211264
#define PW_BYTES 73728

// ---------------------------------------------------------------------------
// Pack activations: bit=1 means sign(x) == -1 (sign bit of fp32).
// Thread mapping t = ((n*56+h)*4+word)*56 + w  -> lanes consecutive in w
// so each of the 64 channel loads is coalesced across the wave.
// ---------------------------------------------------------------------------
__global__ __launch_bounds__(256)
void pack_x_kernel(const float* __restrict__ x, u64* __restrict__ px) {
    int t = blockIdx.x * 256 + threadIdx.x;   // [0, 32*56*4*56) = 401408
    int w    = t % W;
    int r    = t / W;
    int word = r & 3;
    int r2   = r >> 2;
    int h    = r2 % H;
    int n    = r2 / H;
    const float* src = x + ((size_t)(n*C_IN + word*64) * HW + h*W + w);
    u64 bits = 0;
    #pragma unroll
    for (int j = 0; j < 64; ++j) {
        u32 b = __float_as_uint(src[(size_t)j * HW]) >> 31;
        bits |= (u64)b << j;
    }
    px[((size_t)((n*H + h)*W + w) << 2) + word] = bits;
}

// ---------------------------------------------------------------------------
// Pack weights: pw[co][tap][word], tap = kh*3+kw, bit c%64 of word c/64.
// ---------------------------------------------------------------------------
__global__ __launch_bounds__(256)
void pack_w_kernel(const float* __restrict__ wt, u64* __restrict__ pw) {
    int t = blockIdx.x * 256 + threadIdx.x;   // [0, 256*9*4) = 9216
    int word = t & 3;
    int tap  = (t >> 2) % 9;
    int co   = t / 36;
    int kh = tap / 3, kw = tap % 3;
    u64 bits = 0;
    for (int j = 0; j < 64; ++j) {
        int c = word*64 + j;
        float v = wt[((size_t)(co*C_IN + c) * 9) + kh*3 + kw];
        bits |= (u64)(__float_as_uint(v) >> 31) << j;
    }
    pw[t] = bits;   // t == (co*9 + tap)*4 + word
}

// ---------------------------------------------------------------------------
// XNOR-popcount conv. Each lane owns one pixel (n,h,w); its 9 taps x 4 words
// (zero-filled at borders) live in 72 VGPRs. Block stages 64 channels of
// packed weights in LDS (18,432 B); reads are wave-uniform -> broadcast.
// Invalid (padding) taps: substitute popcount 128 so they contribute 0.
// y = 9*256 - 2 * sum(popc') exactly.
// ---------------------------------------------------------------------------
__global__ __launch_bounds__(256)
void conv_kernel(const u64* __restrict__ px, const u64* __restrict__ pw,
                 short* __restrict__ y) {
    __shared__ u64 wl[64*36];
    int cobase = blockIdx.y * 64;
    for (int i = threadIdx.x; i < 64*36; i += 256)
        wl[i] = pw[(size_t)cobase*36 + i];

    int p = blockIdx.x * 256 + threadIdx.x;   // [0, 100352), exact
    int n = p / HW;
    int r = p % HW;
    int h = r / W;
    int w = r % W;

    u64 xt[36];
    int valid = 0;
    #pragma unroll
    for (int kh = 0; kh < 3; ++kh) {
        #pragma unroll
        for (int kw = 0; kw < 3; ++kw) {
            int t  = kh*3 + kw;
            int hh = h + kh - 1;
            int ww = w + kw - 1;
            bool ok = ((unsigned)hh < (unsigned)H) && ((unsigned)ww < (unsigned)W);
            if (ok) {
                const u64* s = px + ((size_t)((n*H + hh)*W + ww) << 2);
                xt[t*4+0] = s[0]; xt[t*4+1] = s[1];
                xt[t*4+2] = s[2]; xt[t*4+3] = s[3];
                valid |= 1 << t;
            } else {
                xt[t*4+0] = 0; xt[t*4+1] = 0; xt[t*4+2] = 0; xt[t*4+3] = 0;
            }
        }
    }
    __syncthreads();

    short* yout = y + (size_t)n*CHW + (size_t)cobase*HW + r;
    for (int ci = 0; ci < 64; ++ci) {
        const u64* wp = &wl[ci*36];
        int acc = 0;
        #pragma unroll
        for (int t = 0; t < 9; ++t) {
            int pc = __popcll(xt[t*4+0] ^ wp[t*4+0])
                   + __popcll(xt[t*4+1] ^ wp[t*4+1])
                   + __popcll(xt[t*4+2] ^ wp[t*4+2])
                   + __popcll(xt[t*4+3] ^ wp[t*4+3]);
            acc += ((valid >> t) & 1) ? pc : 128;
        }
        yout[(size_t)ci * HW] = (short)(2304 - 2*acc);
    }
}

// ---------------------------------------------------------------------------
// BatchNorm (training-mode stats) fused: one block per output channel.
// Phase 1: exact integer sum / sumsq over all N*H*W values of this channel.
// Phase 2: thread 0 computes a = gamma*rsqrt(var+eps), b = beta - mean*a.
// Phase 3: out = a*y + b (channel data ~200 KB, second read mostly L2-hot).
// ---------------------------------------------------------------------------
__global__ __launch_bounds__(1024)
void bn_kernel(const short* __restrict__ y, const float* __restrict__ gamma,
               const float* __restrict__ beta, float* __restrict__ out) {
    int co = blockIdx.x;
    const short* yc = y   + (size_t)co * HW;
    float*       oc = out + (size_t)co * HW;

    int s = 0;
    int ssl = 0;   // per-thread <=128 elems * 2304^2 < 2^31: int32 safe
    for (int n = 0; n < N_IMG; ++n) {
        const short* yn = yc + (size_t)n * CHW;
        for (int i = threadIdx.x; i < HW; i += 1024) {
            int v = yn[i];
            s   += v;
            ssl += v*v;
        }
    }

    __shared__ int       rs [1024];
    __shared__ long long rss[1024];
    rs [threadIdx.x] = s;
    rss[threadIdx.x] = (long long)ssl;
    __syncthreads();
    for (int off = 512; off > 0; off >>= 1) {
        if (threadIdx.x < off) {
            rs [threadIdx.x] += rs [threadIdx.x + off];
            rss[threadIdx.x] += rss[threadIdx.x + off];
        }
        __syncthreads();
    }

    __shared__ float sa, sb;
    if (threadIdx.x == 0) {
        double mean = (double)rs[0]  * (1.0 / (double)NHW);
        double var  = (double)rss[0] * (1.0 / (double)NHW) - mean*mean;
        float inv = rsqrtf((float)var + 1e-5f);
        float a = gamma[co] * inv;
        sa = a;
        sb = beta[co] - (float)mean * a;
    }
    __syncthreads();
    float a = sa, b = sb;

    for (int n = 0; n < N_IMG; ++n) {
        const short* yn = yc + (size_t)n * CHW;
        float*       on = oc + (size_t)n * CHW;
        for (int i = threadIdx.x; i < HW; i += 1024)
            on[i] = a * (float)yn[i] + b;
    }
}

// ---------------------------------------------------------------------------
extern "C" void kernel_launch(void* const* d_in, const int* in_sizes, int n_in,
                              void* d_out, int out_size, void* d_ws, size_t ws_size,
                              hipStream_t stream) {
    const float* x     = (const float*)d_in[0];
    const float* wt    = (const float*)d_in[1];
    const float* gamma = (const float*)d_in[2];
    const float* beta  = (const float*)d_in[3];
    float* out = (float*)d_out;

    char* ws = (char*)d_ws;
    u64*   px = (u64*)ws;
    u64*   pw = (u64*)(ws + PX_BYTES);
    short* y  = (short*)(ws + PX_BYTES + PW_BYTES);

    hipLaunchKernelGGL(pack_x_kernel, dim3(401408/256), dim3(256), 0, stream, x, px);
    hipLaunchKernelGGL(pack_w_kernel, dim3(9216/256),   dim3(256), 0, stream, wt, pw);
    hipLaunchKernelGGL(conv_kernel,   dim3(392, 4),     dim3(256), 0, stream, px, pw, y);
    hipLaunchKernelGGL(bn_kernel,     dim3(C_OUT),      dim3(1024), 0, stream, y, gamma, beta, out);
}

// Round 2
// 377.666 us; speedup vs baseline: 1.1292x; 1.1292x over previous
//
#include <hip/hip_runtime.h>
#include <stdint.h>

typedef unsigned long long u64;
typedef unsigned int u32;

#define N_IMG 32
#define C_IN  256
#define C_OUT 256
#define H     56
#define W     56
#define HW    (H*W)          // 3136
#define NHW   (N_IMG*HW)     // 100352
#define CHW   (C_IN*HW)      // 802816

// Workspace layout:
//   px: [n][h][w][4] u64 packed sign bits of x      (401408 * 8 = 3,211,264 B)
//   pw: [co][tap(9)][4] u64                         (9216   * 8 =    73,728 B)
//   y : [n][co][h][w] int16 exact conv result       (25,690,112 * 2 = 51,380,224 B)
//   partials: overlaps px (px dead after conv) — [8192][2] long long = 131,072 B
#define PX_BYTES 3211264
#define PW_BYTES 73728

// ---------------------------------------------------------------------------
// Pack activations, 4 pixels per thread via float4. bit=1 <=> sign(x)==-1.
// t -> (n, h, word, w4): lanes consecutive in w4 -> 1KB/wave coalesced loads.
// ---------------------------------------------------------------------------
__global__ __launch_bounds__(256)
void pack_x_kernel(const float* __restrict__ x, u64* __restrict__ px) {
    int t = blockIdx.x * 256 + threadIdx.x;   // [0, 32*56*4*14) = 100352
    int w4   = t % 14;
    int r    = t / 14;
    int word = r & 3;
    int r2   = r >> 2;
    int h    = r2 % H;
    int n    = r2 / H;
    const float4* src = (const float4*)(x + ((size_t)(n*C_IN + word*64) * HW + h*W + w4*4));
    u64 b0 = 0, b1 = 0, b2 = 0, b3 = 0;
    #pragma unroll 8
    for (int j = 0; j < 64; ++j) {
        float4 v = src[(size_t)j * (HW/4)];
        b0 |= (u64)(__float_as_uint(v.x) >> 31) << j;
        b1 |= (u64)(__float_as_uint(v.y) >> 31) << j;
        b2 |= (u64)(__float_as_uint(v.z) >> 31) << j;
        b3 |= (u64)(__float_as_uint(v.w) >> 31) << j;
    }
    u64* dst = px + (((size_t)((n*H + h)*W + w4*4)) << 2) + word;
    dst[0] = b0; dst[4] = b1; dst[8] = b2; dst[12] = b3;
}

// ---------------------------------------------------------------------------
// Pack weights: pw[co][tap][word], tap = kh*3+kw, bit c%64 of word c/64.
// ---------------------------------------------------------------------------
__global__ __launch_bounds__(256)
void pack_w_kernel(const float* __restrict__ wt, u64* __restrict__ pw) {
    int t = blockIdx.x * 256 + threadIdx.x;   // [0, 256*9*4) = 9216
    int word = t & 3;
    int tap  = (t >> 2) % 9;
    int co   = t / 36;
    int kh = tap / 3, kw = tap % 3;
    u64 bits = 0;
    for (int j = 0; j < 64; ++j) {
        int c = word*64 + j;
        float v = wt[((size_t)(co*C_IN + c) * 9) + kh*3 + kw];
        bits |= (u64)(__float_as_uint(v) >> 31) << j;
    }
    pw[t] = bits;   // t == (co*9 + tap)*4 + word
}

// ---------------------------------------------------------------------------
// XNOR-popcount conv. 36 tap words in EXPLICIT named registers (R0's u64[36]
// array was demoted to scratch: VGPR_Count=56 < 72 needed -> 7.4 GB of L2
// scratch re-reads). Padding taps: clamped-address load + per-tap mask m_t
// (-1/0): acc = 128*n_invalid + sum(pc_t & m_t). Weights read directly from
// global with wave-uniform addresses -> s_load broadcast, no LDS.
// ---------------------------------------------------------------------------
__global__ __launch_bounds__(256, 2)
void conv_kernel(const u64* __restrict__ px, const u64* __restrict__ pw,
                 short* __restrict__ y) {
    int p = blockIdx.x * 256 + threadIdx.x;   // [0, 100352)
    int n = p / HW;
    int r = p % HW;
    int h = r / W;
    int w = r % W;
    int cobase = blockIdx.y * 64;

    int acc0 = 0;

#define LOADTAP(T, KH, KW)                                                  \
    u64 xa##T, xb##T, xc##T, xd##T; int m##T;                               \
    {                                                                       \
        int hh = h + (KH) - 1, ww = w + (KW) - 1;                           \
        bool ok = ((unsigned)hh < (unsigned)H) && ((unsigned)ww < (unsigned)W); \
        int hc = ok ? hh : 0, wc = ok ? ww : 0;                             \
        const u64* s = px + (((size_t)((n*H + hc)*W + wc)) << 2);           \
        xa##T = s[0]; xb##T = s[1]; xc##T = s[2]; xd##T = s[3];             \
        m##T = ok ? -1 : 0;                                                 \
        acc0 += ok ? 0 : 128;                                               \
    }

    LOADTAP(0, 0, 0) LOADTAP(1, 0, 1) LOADTAP(2, 0, 2)
    LOADTAP(3, 1, 0) LOADTAP(4, 1, 1) LOADTAP(5, 1, 2)
    LOADTAP(6, 2, 0) LOADTAP(7, 2, 1) LOADTAP(8, 2, 2)
#undef LOADTAP

    const u64* wq = pw + (size_t)cobase * 36;
    short* yout = y + (size_t)n*CHW + (size_t)cobase*HW + r;

    for (int ci = 0; ci < 64; ++ci) {
        const u64* q = wq + ci*36;   // wave-uniform -> scalar loads
        int acc = acc0;
#define TAP(T)                                                              \
        {                                                                   \
            int pc = __popcll(xa##T ^ q[(T)*4+0])                           \
                   + __popcll(xb##T ^ q[(T)*4+1])                           \
                   + __popcll(xc##T ^ q[(T)*4+2])                           \
                   + __popcll(xd##T ^ q[(T)*4+3]);                          \
            acc += pc & m##T;                                               \
        }
        TAP(0) TAP(1) TAP(2) TAP(3) TAP(4) TAP(5) TAP(6) TAP(7) TAP(8)
#undef TAP
        yout[(size_t)ci * HW] = (short)(2304 - 2*acc);
    }
}

// ---------------------------------------------------------------------------
// Stats pass: one block per (n,co) slab (3136 contiguous shorts), int4 loads
// (8 shorts), block-reduce, write per-slab partials (no atomics, no memset).
// ---------------------------------------------------------------------------
__global__ __launch_bounds__(256)
void stats_kernel(const short* __restrict__ y, long long* __restrict__ partials) {
    int slab = blockIdx.x;                    // n*256 + co
    const int4* ys = (const int4*)(y + (size_t)slab * HW);
    int s = 0, sq = 0;                        // per-thread <=16 vals: int32-safe
    for (int i = threadIdx.x; i < HW/8; i += 256) {   // 392 int4 per slab
        int4 v = ys[i];
        int vv[4] = {v.x, v.y, v.z, v.w};
        #pragma unroll
        for (int k = 0; k < 4; ++k) {
            int lo = (short)(vv[k] & 0xFFFF);
            int hi = (short)(vv[k] >> 16);
            s  += lo + hi;
            sq += lo*lo + hi*hi;
        }
    }
    __shared__ int       rs[256];
    __shared__ long long rq[256];
    rs[threadIdx.x] = s;
    rq[threadIdx.x] = sq;
    __syncthreads();
    for (int off = 128; off > 0; off >>= 1) {
        if (threadIdx.x < off) {
            rs[threadIdx.x] += rs[threadIdx.x + off];
            rq[threadIdx.x] += rq[threadIdx.x + off];
        }
        __syncthreads();
    }
    if (threadIdx.x == 0) {
        partials[2*slab]   = rs[0];
        partials[2*slab+1] = rq[0];
    }
}

// ---------------------------------------------------------------------------
// Apply pass: one block per (n,co) slab. Reduce the 32 per-image partials of
// this channel (uniform scalar loads), compute a,b, vectorized normalize.
// ---------------------------------------------------------------------------
__global__ __launch_bounds__(256)
void apply_kernel(const short* __restrict__ y, const long long* __restrict__ partials,
                  const float* __restrict__ gamma, const float* __restrict__ beta,
                  float* __restrict__ out) {
    int slab = blockIdx.x;
    int co = slab & 255;
    long long S = 0, SS = 0;
    #pragma unroll 8
    for (int m = 0; m < N_IMG; ++m) {
        S  += partials[2*((m<<8) | co)];
        SS += partials[2*((m<<8) | co) + 1];
    }
    double mean = (double)S  * (1.0 / (double)NHW);
    double var  = (double)SS * (1.0 / (double)NHW) - mean*mean;
    float a = gamma[co] * rsqrtf((float)var + 1e-5f);
    float b = beta[co] - (float)mean * a;

    const int4* ys = (const int4*)(y + (size_t)slab * HW);
    float4*     os = (float4*)(out + (size_t)slab * HW);
    for (int i = threadIdx.x; i < HW/8; i += 256) {
        int4 v = ys[i];
        float4 f0, f1;
        f0.x = a * (float)((short)(v.x & 0xFFFF)) + b;
        f0.y = a * (float)((short)(v.x >> 16))    + b;
        f0.z = a * (float)((short)(v.y & 0xFFFF)) + b;
        f0.w = a * (float)((short)(v.y >> 16))    + b;
        f1.x = a * (float)((short)(v.z & 0xFFFF)) + b;
        f1.y = a * (float)((short)(v.z >> 16))    + b;
        f1.z = a * (float)((short)(v.w & 0xFFFF)) + b;
        f1.w = a * (float)((short)(v.w >> 16))    + b;
        os[2*i]   = f0;
        os[2*i+1] = f1;
    }
}

// ---------------------------------------------------------------------------
extern "C" void kernel_launch(void* const* d_in, const int* in_sizes, int n_in,
                              void* d_out, int out_size, void* d_ws, size_t ws_size,
                              hipStream_t stream) {
    const float* x     = (const float*)d_in[0];
    const float* wt    = (const float*)d_in[1];
    const float* gamma = (const float*)d_in[2];
    const float* beta  = (const float*)d_in[3];
    float* out = (float*)d_out;

    char* ws = (char*)d_ws;
    u64*   px = (u64*)ws;
    u64*   pw = (u64*)(ws + PX_BYTES);
    short* y  = (short*)(ws + PX_BYTES + PW_BYTES);
    long long* partials = (long long*)ws;   // overlaps px: px dead after conv

    hipLaunchKernelGGL(pack_x_kernel, dim3(100352/256), dim3(256), 0, stream, x, px);
    hipLaunchKernelGGL(pack_w_kernel, dim3(9216/256),   dim3(256), 0, stream, wt, pw);
    hipLaunchKernelGGL(conv_kernel,   dim3(392, 4),     dim3(256), 0, stream, px, pw, y);
    hipLaunchKernelGGL(stats_kernel,  dim3(8192),       dim3(256), 0, stream, y, partials);
    hipLaunchKernelGGL(apply_kernel,  dim3(8192),       dim3(256), 0, stream, y, partials, gamma, beta, out);
}